// Round 6
// baseline (198.676 us; speedup 1.0000x reference)
//
#include <hip/hip_runtime.h>
#include <math.h>

// ---------------------------------------------------------------------------
// LTFGW: N=4096, K=16 (k1=17), T=16, NT=16, D=128, OUTER=3, INNER=5.
//
// R6: adj is {0,1}-valued -> bit-pack it (2 MB, L2-resident) in prep; the
//     1.18M-random-read c1gather then hits L2-hot packed words instead of
//     64MB of HBM with 16x line overfetch. Main kernel = R4 verbatim
//     (absmax 0.0; R5's exp2-fma fold reverted — it cost margin 0->0.5).
// Dispatches: 1) pgemm + adjpack + xsq + scalars  2) c1gather_packed  3) main.
// R2/R3 lesson (kept): no LDS vector loads of C1 inside unrolled branches —
// scheduler hoists ~270 VGPRs of ds_read results -> 0.5-1 GB scratch spill.
// ---------------------------------------------------------------------------

#define NN 4096
#define KNB 16
#define K1 17
#define C1STRIDE 20   // C1 row: 17 vals + cc1@17 + mask@18(row0) + pad
#define C1NODE 340
#define TSTR 296      // Ksh per-template stride; 296%32==8 -> 2-way banks
#define TINYF 1e-16f

typedef const __attribute__((address_space(4))) float* c4fp;
typedef const __attribute__((address_space(4))) int*   c4ip;
__device__ __forceinline__ float sload(const float* p){ return *(c4fp)(unsigned long long)p; }
__device__ __forceinline__ int   sloadi(const int* p) { return *(c4ip)(unsigned long long)p; }

template<int CTRL>
__device__ __forceinline__ float dppmov(float x) {
  return __int_as_float(
      __builtin_amdgcn_update_dpp(0, __float_as_int(x), CTRL, 0xF, 0xF, true));
}
__device__ __forceinline__ float xor4v(float x) {        // xor4 = xor7 then xor3
  return dppmov<0x1B>(dppmov<0x141>(x));
}
__device__ __forceinline__ float rsum16(float x) {
  x += dppmov<0xB1>(x); x += dppmov<0x4E>(x);
  x += xor4v(x);        x += dppmov<0x128>(x);
  return x;
}
__device__ __forceinline__ float rmin16(float x) {
  x = fminf(x, dppmov<0xB1>(x)); x = fminf(x, dppmov<0x4E>(x));
  x = fminf(x, xor4v(x));        x = fminf(x, dppmov<0x128>(x));
  return x;
}
__device__ __forceinline__ float rmax16(float x) {
  x = fmaxf(x, dppmov<0xB1>(x)); x = fmaxf(x, dppmov<0x4E>(x));
  x = fmaxf(x, xor4v(x));        x = fmaxf(x, dppmov<0x128>(x));
  return x;
}
__device__ __forceinline__ float rcpn(float x) {   // rcp + 1 Newton step
  float r = __builtin_amdgcn_rcpf(x);
  return r * (2.f - x * r);
}

// cumulative XOR walk (verified R1/R4, absmax 0): after step r, g = src lane l^r
#define WSTEP(C, R) { g = dppmov<C>(g); acc = fmaf(g, c2reg[R], acc); }
#define WALK15() \
  WSTEP(0xB1,1)  WSTEP(0x1B,2)  WSTEP(0xB1,3)  WSTEP(0x141,4) \
  WSTEP(0xB1,5)  WSTEP(0x1B,6)  WSTEP(0xB1,7)  WSTEP(0x140,8) \
  WSTEP(0xB1,9)  WSTEP(0x1B,10) WSTEP(0xB1,11) WSTEP(0x141,12) \
  WSTEP(0xB1,13) WSTEP(0x1B,14) WSTEP(0xB1,15)

// ---------------------------------------------------------------------------
// prep_combined: one dispatch, block-range partitioned.
//   blocks [0,256)     : pgemm  P = x @ tf^T            (VALU/LDS-bound)
//   blocks [256,1280)  : adjpack -> 2 MB bitmask        (HBM-BW-bound, 67 MB)
//   blocks [1280,2304) : xsq[n] = ||x[n]||^2            (trivial)
//   block  2304        : scalars (alpha,q,cq,tfsq)
// ---------------------------------------------------------------------------
#define PG_GEMM  256
#define PG_PACK  (PG_GEMM + 1024)        // 1280
#define PG_XSQ   (PG_PACK + 1024)        // 2304
#define PG_SCAL  PG_XSQ                   // block 2304
#define PG_TOT   (PG_SCAL + 1)            // 2305

__global__ __launch_bounds__(256) void prep_combined(
    const float* __restrict__ x, const float* __restrict__ adj,
    const float* __restrict__ templates_, const float* __restrict__ tf,
    const float* __restrict__ q0, const float* __restrict__ alpha0,
    float* __restrict__ P, unsigned long long* __restrict__ pk,
    float* __restrict__ xsq, float* __restrict__ tfsq,
    float* __restrict__ qmat, float* __restrict__ cq,
    float* __restrict__ walpha) {
  __shared__ __align__(16) float smem[2 * 64 * 68];   // 34816 B arena (pgemm)
  const int b = blockIdx.x, tid = threadIdx.x;

  if (b < PG_GEMM) {
    // ---- pgemm: 64x64 tile, 4x4 per thread ----
    float (*As)[68] = (float (*)[68])smem;
    float (*Bs)[68] = (float (*)[68])(smem + 64 * 68);
    int tx = tid & 15, ty = tid >> 4;
    int r0 = (b & 63) * 64, c0 = (b >> 6) * 64;
    float acc[4][4] = {};
    for (int h = 0; h < 2; ++h) {
      __syncthreads();
#pragma unroll
      for (int q = 0; q < 4; ++q) {
        int f = tid + 256*q;
        int row = f >> 4, d4 = (f & 15) << 2;
        float4 a = *(const float4*)&x[(r0+row)*128 + h*64 + d4];
        As[d4+0][row]=a.x; As[d4+1][row]=a.y; As[d4+2][row]=a.z; As[d4+3][row]=a.w;
        float4 bb = *(const float4*)&tf[(c0+row)*128 + h*64 + d4];
        Bs[d4+0][row]=bb.x; Bs[d4+1][row]=bb.y; Bs[d4+2][row]=bb.z; Bs[d4+3][row]=bb.w;
      }
      __syncthreads();
#pragma unroll
      for (int d = 0; d < 64; ++d) {
        float4 a = *(const float4*)&As[d][ty*4];
        float4 bb = *(const float4*)&Bs[d][tx*4];
        float av[4]={a.x,a.y,a.z,a.w}, bv[4]={bb.x,bb.y,bb.z,bb.w};
#pragma unroll
        for (int i = 0; i < 4; ++i)
#pragma unroll
          for (int j = 0; j < 4; ++j) acc[i][j] = fmaf(av[i], bv[j], acc[i][j]);
      }
    }
#pragma unroll
    for (int i = 0; i < 4; ++i) {
      float4 o; o.x=acc[i][0]; o.y=acc[i][1]; o.z=acc[i][2]; o.w=acc[i][3];
      *(float4*)&P[(r0 + ty*4 + i)*256 + c0 + tx*4] = o;
    }
    return;
  }

  if (b < PG_PACK) {
    // ---- adjpack: 64 consecutive adj floats -> one 64-bit ballot word ----
    // ull word w covers columns 64*(w%64).. of row w/64 (4096 cols = 64 ull).
    int wave = (b - PG_GEMM)*4 + (tid >> 6);   // 0..4095
    int lane = tid & 63;
#pragma unroll 4
    for (int it = 0; it < 64; ++it) {
      int w64 = wave + it*4096;                 // 0..262143
      float v = adj[(size_t)w64*64 + lane];
      unsigned long long m = __ballot(v != 0.f);
      if (lane == 0) pk[w64] = m;
    }
    return;
  }

  if (b < PG_XSQ) {
    // ---- xsq: 4 rows per block, 1 wave per row ----
    int n = (b - PG_PACK)*4 + (tid >> 6), lane = tid & 63;
    float2 v = *(const float2*)&x[n*128 + lane*2];
    float s = fmaf(v.x, v.x, v.y*v.y);
    s += __shfl_xor(s,1); s += __shfl_xor(s,2);  s += __shfl_xor(s,4);
    s += __shfl_xor(s,8); s += __shfl_xor(s,16); s += __shfl_xor(s,32);
    if (lane == 0) xsq[n] = s;
    return;
  }

  // ---- scalars: alpha, q=softmax(q0), cq, tfsq ----
  {
    int t = tid >> 4, l = tid & 15;
    if (tid == 0) walpha[0] = 1.f / (1.f + expf(-alpha0[0]));
    float qr[16]; float mx = -3.0e38f;
#pragma unroll
    for (int m = 0; m < 16; ++m) { qr[m] = q0[t*16+m]; mx = fmaxf(mx, qr[m]); }
    float s = 0.f;
#pragma unroll
    for (int m = 0; m < 16; ++m) { qr[m] = expf(qr[m]-mx); s += qr[m]; }
    float inv = 1.f / s;
    qmat[tid] = qr[l] * inv;
    float c = 0.f;
#pragma unroll
    for (int m = 0; m < 16; ++m) {
      float c2 = templates_[t*256 + l*16 + m];
      c = fmaf(qr[m]*inv, c2*c2, c);
    }
    cq[tid] = c;
    float ts = 0.f;
#pragma unroll
    for (int dq = 0; dq < 32; ++dq) {
      float4 v = *(const float4*)&tf[tid*128 + dq*4];
      ts = fmaf(v.x,v.x,ts); ts = fmaf(v.y,v.y,ts);
      ts = fmaf(v.z,v.z,ts); ts = fmaf(v.w,v.w,ts);
    }
    tfsq[tid] = ts;
  }
}

// ---------------------------------------------------------------------------
// c1gather_packed: C1ws[n][i][j] = bit(pk[nb_i], nb_j) as float (exact adj
// value); cc1@17; nz-row mask@18. Reads hit the 2 MB L2-hot pack.
// ---------------------------------------------------------------------------
__global__ __launch_bounds__(256) void c1gather_packed(
    const unsigned* __restrict__ pku, const int* __restrict__ neighbors,
    float* __restrict__ C1ws) {
  __shared__ int nbs[K1];
  __shared__ float c1sh[K1 * K1];
  int n = blockIdx.x;
  int tid = threadIdx.x;
  if (tid < K1) nbs[tid] = (tid == 0) ? n : neighbors[n*KNB + tid - 1];
  __syncthreads();
  for (int e = tid; e < 289; e += 256) {
    int i = e / 17, j = e % 17;
    int col = nbs[j];
    unsigned w = pku[nbs[i]*128 + (col >> 5)];
    float v = ((w >> (col & 31)) & 1u) ? 1.f : 0.f;
    C1ws[n*C1NODE + i*C1STRIDE + j] = v;
    c1sh[e] = v;
  }
  __syncthreads();
  bool nz = false;
  if (tid < K1) {
    float s = 0.f;
#pragma unroll
    for (int j = 0; j < K1; ++j) {
      float v = c1sh[tid*17 + j];
      s = fmaf(v, v, s); nz |= (v != 0.f);
    }
    C1ws[n*C1NODE + tid*C1STRIDE + 17] = s * (1.f/17.f);
  }
  unsigned long long bal = __ballot(nz);   // wave 0 holds tid<17
  if (tid == 0)
    ((int*)C1ws)[n*C1NODE + 18] = (int)(bal & 0x1FFFF);
}

// ---------------------------------------------------------------------------
// main: 1 block/node, 256 thr = 16 templates x 16 cols (R4-verified, verbatim).
// ---------------------------------------------------------------------------
__global__ __launch_bounds__(256, 2) void ltfgw_main(
    const float* __restrict__ P, const float* __restrict__ C1ws,
    const float* __restrict__ xsq, const float* __restrict__ tfsq,
    const float* __restrict__ qmat, const float* __restrict__ cq,
    const float* __restrict__ walpha, const int* __restrict__ neighbors,
    const float* __restrict__ templates_, float* __restrict__ out) {
  __shared__ __align__(16) float Ksh[16 * TSTR];
  __shared__ __align__(16) float Ush[256];
  __shared__ __align__(16) float Vsh[256];

  const int tid = threadIdx.x;
  const int t = tid >> 4, l = tid & 15;
  const int n = blockIdx.x;

  const float alpha = sload(walpha);
  const float oma = 1.f - alpha;
  const float na2 = -2.f * alpha;
  const int mask = sloadi((const int*)C1ws + n*C1NODE + 18);

  int nbk[K1];
  nbk[0] = n;
#pragma unroll
  for (int k = 1; k < K1; ++k) nbk[k] = sloadi(neighbors + n*KNB + (k-1));

  const float tfsq_l = tfsq[tid];
  const float cq_l   = cq[tid];
  const float q_l    = qmat[tid];

  // Mcol = (1-a)*M + a*cC ; grad = Mcol - 2a*(C1@G@C2^T)
  float Mcol[K1];
#pragma unroll
  for (int k = 0; k < K1; ++k) {
    float xs  = sload(xsq + nbk[k]);
    float cc1 = sload(C1ws + n*C1NODE + k*C1STRIDE + 17);
    float pv  = P[nbk[k]*256 + tid];
    Mcol[k] = oma * (xs + tfsq_l - 2.f*pv) + alpha * (cc1 + cq_l);
  }

  // c2reg[r] = -2a * C2[t][l][l^r]  (pre-rotated for the XOR walk)
  float c2reg[16];
#pragma unroll
  for (int r = 0; r < 16; ++r)
    c2reg[r] = na2 * templates_[t*256 + l*16 + (l ^ r)];

  // G[j][l] in registers; init p*q
  float Gcol[K1];
#pragma unroll
  for (int j = 0; j < K1; ++j) Gcol[j] = (1.f/17.f) * q_l;

  const int tb = t * TSTR;
  float ur[16], u16 = 0.f, vm = 1.f;

#pragma unroll 1
  for (int outer = 0; outer < 3; ++outer) {
    // grad rows -> Kc[]; only C1-nonzero rows get the matvec + DPP walk
    float Kc[K1];
    float lo = 3.0e38f, hi = -3.0e38f;
#pragma unroll
    for (int i = 0; i < K1; ++i) {
      float gr = Mcol[i];
      if (mask & (1 << i)) {
        const float* c1r = C1ws + n*C1NODE + i*C1STRIDE;
        float s = 0.f;
#pragma unroll
        for (int j = 0; j < K1; ++j) s = fmaf(sload(c1r + j), Gcol[j], s);
        float g = s, acc = s * c2reg[0];
        WALK15()
        gr += acc;
      }
      Kc[i] = gr;
      lo = fminf(lo, gr); hi = fmaxf(hi, gr);
    }
    lo = rmin16(lo); hi = rmax16(hi);
    float eps = 0.1f * (hi - lo) + TINYF;
    float sc = 1.4426950408889634f * __builtin_amdgcn_rcpf(eps);
#pragma unroll
    for (int i = 0; i < K1; ++i) {
      Kc[i] = __builtin_amdgcn_exp2f((lo - Kc[i]) * sc);
      Ksh[tb + i*17 + l] = Kc[i];           // transpose write (same wave)
    }
    // row l of K for the u-update
    float Krow[16];
#pragma unroll
    for (int jq = 0; jq < 4; ++jq) {
      float4 v = *(const float4*)&Ksh[tb + l*17 + jq*4];
      Krow[jq*4+0]=v.x; Krow[jq*4+1]=v.y; Krow[jq*4+2]=v.z; Krow[jq*4+3]=v.w;
    }

    // Sinkhorn: 5 iters (u then v), v0 = 1
    float vlane = 1.f;
    Vsh[tid] = 1.f;
#pragma unroll 1
    for (int it = 0; it < 5; ++it) {
      float vr[16];
#pragma unroll
      for (int q = 0; q < 4; ++q) {
        float4 v = *(const float4*)&Vsh[t*16 + q*4];
        vr[q*4+0]=v.x; vr[q*4+1]=v.y; vr[q*4+2]=v.z; vr[q*4+3]=v.w;
      }
      float w = 0.f;
#pragma unroll
      for (int j = 0; j < 16; ++j) w = fmaf(Krow[j], vr[j], w);
      float w16 = rsum16(Kc[16] * vlane);          // row 16 via DPP
      float um = (1.f/17.f) * rcpn(fmaxf(w,   TINYF));
      u16      = (1.f/17.f) * rcpn(fmaxf(w16, TINYF));
      Ush[tid] = um;
#pragma unroll
      for (int q = 0; q < 4; ++q) {
        float4 v = *(const float4*)&Ush[t*16 + q*4];
        ur[q*4+0]=v.x; ur[q*4+1]=v.y; ur[q*4+2]=v.z; ur[q*4+3]=v.w;
      }
      float sg = u16 * Kc[16];
#pragma unroll
      for (int k = 0; k < 16; ++k) sg = fmaf(ur[k], Kc[k], sg);
      vlane = q_l * rcpn(fmaxf(sg, TINYF));
      Vsh[tid] = vlane;
    }
    vm = vlane;
    // G = u * K * v
#pragma unroll
    for (int k = 0; k < 16; ++k) Gcol[k] = ur[k] * Kc[k] * vm;
    Gcol[16] = u16 * Kc[16] * vm;
  }

  // out[n,t] = sum_{i,l} (Mcol + delta) * G
  float acc1 = 0.f;
#pragma unroll
  for (int i = 0; i < K1; ++i) acc1 = fmaf(Mcol[i], Gcol[i], acc1);
#pragma unroll
  for (int i = 0; i < K1; ++i) {
    if (mask & (1 << i)) {
      const float* c1r = C1ws + n*C1NODE + i*C1STRIDE;
      float s = 0.f;
#pragma unroll
      for (int j = 0; j < K1; ++j) s = fmaf(sload(c1r + j), Gcol[j], s);
      float g = s, acc = s * c2reg[0];
      WALK15()
      acc1 = fmaf(acc, Gcol[i], acc1);
    }
  }
  float accout = rsum16(acc1);
  if (l == 0) out[n*16 + t] = accout;
}

// ---------------------------------------------------------------------------
extern "C" void kernel_launch(void* const* d_in, const int* in_sizes, int n_in,
                              void* d_out, int out_size, void* d_ws, size_t ws_size,
                              hipStream_t stream) {
  const float* x          = (const float*)d_in[0];
  const float* adj        = (const float*)d_in[1];
  const int*   neighbors  = (const int*)  d_in[2];
  const float* templates_ = (const float*)d_in[3];
  const float* tfeat      = (const float*)d_in[4];
  const float* q0         = (const float*)d_in[5];
  const float* alpha0     = (const float*)d_in[6];
  float* out = (float*)d_out;

  float* ws     = (float*)d_ws;
  float* P      = ws;                       // 1048576 floats
  float* C1ws   = P + 4096*256;             // 1392640 floats
  float* xsq    = C1ws + 4096*C1NODE;       // 4096
  float* tfsq   = xsq + 4096;               // 256
  float* qmat   = tfsq + 256;               // 256
  float* cq     = qmat + 256;               // 256
  float* walpha = cq + 256;                 // 8 (padded for alignment)
  unsigned long long* pk = (unsigned long long*)(walpha + 8);  // 262144 ull = 2 MB

  hipLaunchKernelGGL(prep_combined, dim3(PG_TOT), dim3(256), 0, stream,
                     x, adj, templates_, tfeat, q0, alpha0,
                     P, pk, xsq, tfsq, qmat, cq, walpha);
  hipLaunchKernelGGL(c1gather_packed, dim3(4096), dim3(256), 0, stream,
                     (const unsigned*)pk, neighbors, C1ws);
  hipLaunchKernelGGL(ltfgw_main, dim3(4096), dim3(256), 0, stream,
                     P, C1ws, xsq, tfsq, qmat, cq, walpha, neighbors,
                     templates_, out);
}

// Round 7
// 195.414 us; speedup vs baseline: 1.0167x; 1.0167x over previous
//
#include <hip/hip_runtime.h>
#include <math.h>

// ---------------------------------------------------------------------------
// LTFGW: N=4096, K=16 (k1=17), T=16, NT=16, D=128, OUTER=3, INNER=5.
//
// R7: C1 never touches memory. Main gathers 17x17 adjacency BITS from the
//     2 MB L2-resident pack (built in prep), keeps them as 17 uniform row
//     bitmasks; matvec = predicated adds on Gcol regs (nothing to hoist ->
//     no R2/R3 spill path). cc1 = popcount/17 (exact for 0/1 adj).
//     Deletes c1gather dispatch + C1ws buffer entirely. 2 dispatches.
//     pgemm retiled 32x64 (512 blocks, 2/CU) to halve its LDS-pipe time.
// Kept: R4-verified Sinkhorn/Ksh structure (absmax 0.0), exact exp2 form.
// ---------------------------------------------------------------------------

#define NN 4096
#define KNB 16
#define K1 17
#define TSTR 296      // Ksh per-template stride; 296%32==8 -> 2-way banks
#define TINYF 1e-16f

typedef const __attribute__((address_space(4))) float* c4fp;
typedef const __attribute__((address_space(4))) int*   c4ip;
__device__ __forceinline__ float sload(const float* p){ return *(c4fp)(unsigned long long)p; }
__device__ __forceinline__ int   sloadi(const int* p) { return *(c4ip)(unsigned long long)p; }

template<int CTRL>
__device__ __forceinline__ float dppmov(float x) {
  return __int_as_float(
      __builtin_amdgcn_update_dpp(0, __float_as_int(x), CTRL, 0xF, 0xF, true));
}
__device__ __forceinline__ float xor4v(float x) {        // xor4 = xor7 then xor3
  return dppmov<0x1B>(dppmov<0x141>(x));
}
__device__ __forceinline__ float rsum16(float x) {
  x += dppmov<0xB1>(x); x += dppmov<0x4E>(x);
  x += xor4v(x);        x += dppmov<0x128>(x);
  return x;
}
__device__ __forceinline__ float rmin16(float x) {
  x = fminf(x, dppmov<0xB1>(x)); x = fminf(x, dppmov<0x4E>(x));
  x = fminf(x, xor4v(x));        x = fminf(x, dppmov<0x128>(x));
  return x;
}
__device__ __forceinline__ float rmax16(float x) {
  x = fmaxf(x, dppmov<0xB1>(x)); x = fmaxf(x, dppmov<0x4E>(x));
  x = fmaxf(x, xor4v(x));        x = fmaxf(x, dppmov<0x128>(x));
  return x;
}
__device__ __forceinline__ float rcpn(float x) {   // rcp + 1 Newton step
  float r = __builtin_amdgcn_rcpf(x);
  return r * (2.f - x * r);
}

// cumulative XOR walk (verified R1/R4, absmax 0): after step r, g = src lane l^r
#define WSTEP(C, R) { g = dppmov<C>(g); acc = fmaf(g, c2reg[R], acc); }
#define WALK15() \
  WSTEP(0xB1,1)  WSTEP(0x1B,2)  WSTEP(0xB1,3)  WSTEP(0x141,4) \
  WSTEP(0xB1,5)  WSTEP(0x1B,6)  WSTEP(0xB1,7)  WSTEP(0x140,8) \
  WSTEP(0xB1,9)  WSTEP(0x1B,10) WSTEP(0xB1,11) WSTEP(0x141,12) \
  WSTEP(0xB1,13) WSTEP(0x1B,14) WSTEP(0xB1,15)

// ---------------------------------------------------------------------------
// prep_combined: one dispatch, block-range partitioned (all parts independent).
//   blocks [0,512)     : pgemm  P = x @ tf^T, 32x64 tiles  (LDS-pipe-bound)
//   blocks [512,1536)  : adjpack -> 2 MB bitmask           (HBM-BW-bound)
//   blocks [1536,2560) : xsq[n] = ||x[n]||^2               (trivial)
//   block  2560        : scalars (alpha,q,cq,tfsq)
// ---------------------------------------------------------------------------
#define PG_GEMM  512
#define PG_PACK  (PG_GEMM + 1024)        // 1536
#define PG_XSQ   (PG_PACK + 1024)        // 2560
#define PG_SCAL  PG_XSQ                   // block 2560
#define PG_TOT   (PG_SCAL + 1)            // 2561

__global__ __launch_bounds__(256) void prep_combined(
    const float* __restrict__ x, const float* __restrict__ adj,
    const float* __restrict__ templates_, const float* __restrict__ tf,
    const float* __restrict__ q0, const float* __restrict__ alpha0,
    float* __restrict__ P, unsigned long long* __restrict__ pk,
    float* __restrict__ xsq, float* __restrict__ tfsq,
    float* __restrict__ qmat, float* __restrict__ cq,
    float* __restrict__ walpha) {
  __shared__ __align__(16) float smem[2 * 64 * 68];   // 34816 B arena
  const int b = blockIdx.x, tid = threadIdx.x;

  if (b < PG_GEMM) {
    // ---- pgemm: 32 rows x 64 cols per block, 2x4 per thread ----
    float (*As)[68] = (float (*)[68])smem;            // [d][row], rows 0..31
    float (*Bs)[68] = (float (*)[68])(smem + 64*68);  // [d][col], cols 0..63
    int tx = tid & 15, ty = tid >> 4;
    int r0 = (b & 127) * 32, c0 = (b >> 7) * 64;
    float acc[2][4] = {};
    for (int h = 0; h < 2; ++h) {
      __syncthreads();
#pragma unroll
      for (int q = 0; q < 2; ++q) {                  // A: 512 float4
        int f = tid + 256*q;
        int row = f >> 4, d4 = (f & 15) << 2;
        float4 a = *(const float4*)&x[(r0+row)*128 + h*64 + d4];
        As[d4+0][row]=a.x; As[d4+1][row]=a.y; As[d4+2][row]=a.z; As[d4+3][row]=a.w;
      }
#pragma unroll
      for (int q = 0; q < 4; ++q) {                  // B: 1024 float4
        int f = tid + 256*q;
        int col = f >> 4, d4 = (f & 15) << 2;
        float4 bb = *(const float4*)&tf[(c0+col)*128 + h*64 + d4];
        Bs[d4+0][col]=bb.x; Bs[d4+1][col]=bb.y; Bs[d4+2][col]=bb.z; Bs[d4+3][col]=bb.w;
      }
      __syncthreads();
#pragma unroll
      for (int d = 0; d < 64; ++d) {
        float2 a = *(const float2*)&As[d][ty*2];
        float4 bb = *(const float4*)&Bs[d][tx*4];
        float av[2]={a.x,a.y}, bv[4]={bb.x,bb.y,bb.z,bb.w};
#pragma unroll
        for (int i = 0; i < 2; ++i)
#pragma unroll
          for (int j = 0; j < 4; ++j) acc[i][j] = fmaf(av[i], bv[j], acc[i][j]);
      }
    }
#pragma unroll
    for (int i = 0; i < 2; ++i) {
      float4 o; o.x=acc[i][0]; o.y=acc[i][1]; o.z=acc[i][2]; o.w=acc[i][3];
      *(float4*)&P[(r0 + ty*2 + i)*256 + c0 + tx*4] = o;
    }
    return;
  }

  if (b < PG_PACK) {
    // ---- adjpack: 64 consecutive adj floats -> one 64-bit ballot word ----
    int wave = (b - PG_GEMM)*4 + (tid >> 6);   // 0..4095
    int lane = tid & 63;
#pragma unroll 4
    for (int it = 0; it < 64; ++it) {
      int w64 = wave + it*4096;                 // 0..262143
      float v = adj[(size_t)w64*64 + lane];
      unsigned long long m = __ballot(v != 0.f);
      if (lane == 0) pk[w64] = m;
    }
    return;
  }

  if (b < PG_XSQ) {
    // ---- xsq: 4 rows per block, 1 wave per row ----
    int n = (b - PG_PACK)*4 + (tid >> 6), lane = tid & 63;
    float2 v = *(const float2*)&x[n*128 + lane*2];
    float s = fmaf(v.x, v.x, v.y*v.y);
    s += __shfl_xor(s,1); s += __shfl_xor(s,2);  s += __shfl_xor(s,4);
    s += __shfl_xor(s,8); s += __shfl_xor(s,16); s += __shfl_xor(s,32);
    if (lane == 0) xsq[n] = s;
    return;
  }

  // ---- scalars: alpha, q=softmax(q0), cq, tfsq ----
  {
    int t = tid >> 4, l = tid & 15;
    if (tid == 0) walpha[0] = 1.f / (1.f + expf(-alpha0[0]));
    float qr[16]; float mx = -3.0e38f;
#pragma unroll
    for (int m = 0; m < 16; ++m) { qr[m] = q0[t*16+m]; mx = fmaxf(mx, qr[m]); }
    float s = 0.f;
#pragma unroll
    for (int m = 0; m < 16; ++m) { qr[m] = expf(qr[m]-mx); s += qr[m]; }
    float inv = 1.f / s;
    qmat[tid] = qr[l] * inv;
    float c = 0.f;
#pragma unroll
    for (int m = 0; m < 16; ++m) {
      float c2 = templates_[t*256 + l*16 + m];
      c = fmaf(qr[m]*inv, c2*c2, c);
    }
    cq[tid] = c;
    float ts = 0.f;
#pragma unroll
    for (int dq = 0; dq < 32; ++dq) {
      float4 v = *(const float4*)&tf[tid*128 + dq*4];
      ts = fmaf(v.x,v.x,ts); ts = fmaf(v.y,v.y,ts);
      ts = fmaf(v.z,v.z,ts); ts = fmaf(v.w,v.w,ts);
    }
    tfsq[tid] = ts;
  }
}

// ---------------------------------------------------------------------------
// main: 1 block/node, 256 thr = 16 templates x 16 cols. C1 as 17 row
// bitmasks gathered from the L2-hot pack; matvec = predicated Gcol adds.
// ---------------------------------------------------------------------------
__global__ __launch_bounds__(256, 2) void ltfgw_main(
    const float* __restrict__ P, const unsigned* __restrict__ pku,
    const float* __restrict__ xsq, const float* __restrict__ tfsq,
    const float* __restrict__ qmat, const float* __restrict__ cq,
    const float* __restrict__ walpha, const int* __restrict__ neighbors,
    const float* __restrict__ templates_, float* __restrict__ out) {
  __shared__ __align__(16) float Ksh[16 * TSTR];
  __shared__ __align__(16) float Ush[256];
  __shared__ __align__(16) float Vsh[256];
  __shared__ int rowm[20];

  const int tid = threadIdx.x;
  const int t = tid >> 4, l = tid & 15;
  const int n = blockIdx.x;

  const float alpha = sload(walpha);
  const float oma = 1.f - alpha;
  const float na2 = -2.f * alpha;

  int nbk[K1];
  nbk[0] = n;
#pragma unroll
  for (int k = 1; k < K1; ++k) nbk[k] = sloadi(neighbors + n*KNB + (k-1));

  // gather C1 row bitmasks from the 2 MB pack (L2-hot): thread i -> row i
  if (tid < K1) {
    int row = (tid == 0) ? n : neighbors[n*KNB + tid - 1];
    const unsigned* prow = pku + row*128;
    unsigned m = 0;
#pragma unroll
    for (int j = 0; j < K1; ++j) {
      int col = nbk[j];
      unsigned w = prow[col >> 5];
      m |= ((w >> (col & 31)) & 1u) << j;
    }
    rowm[tid] = (int)m;
  }
  __syncthreads();
  int rmv[K1];
#pragma unroll
  for (int i = 0; i < K1; ++i) rmv[i] = rowm[i];   // LDS broadcast, uniform

  const float tfsq_l = tfsq[tid];
  const float cq_l   = cq[tid];
  const float q_l    = qmat[tid];

  // Mcol = (1-a)*M + a*cC ; cc1_k = popcount(row_k)/17 (C1 is 0/1 -> exact)
  float Mcol[K1];
#pragma unroll
  for (int k = 0; k < K1; ++k) {
    float xs  = sload(xsq + nbk[k]);
    float cc1 = (float)__popc((unsigned)rmv[k]) * (1.f/17.f);
    float pv  = P[nbk[k]*256 + tid];
    Mcol[k] = oma * (xs + tfsq_l - 2.f*pv) + alpha * (cc1 + cq_l);
  }

  // c2reg[r] = -2a * C2[t][l][l^r]  (pre-rotated for the XOR walk)
  float c2reg[16];
#pragma unroll
  for (int r = 0; r < 16; ++r)
    c2reg[r] = na2 * templates_[t*256 + l*16 + (l ^ r)];

  // G[j][l] in registers; init p*q
  float Gcol[K1];
#pragma unroll
  for (int j = 0; j < K1; ++j) Gcol[j] = (1.f/17.f) * q_l;

  const int tb = t * TSTR;
  float ur[16], u16 = 0.f, vm = 1.f;

#pragma unroll 1
  for (int outer = 0; outer < 3; ++outer) {
    // grad rows -> Kc[]; only rows with C1 bits get the matvec + DPP walk
    float Kc[K1];
    float lo = 3.0e38f, hi = -3.0e38f;
#pragma unroll
    for (int i = 0; i < K1; ++i) {
      float gr = Mcol[i];
      int rmi = __builtin_amdgcn_readfirstlane(rmv[i]);
      if (rmi) {
        float s = 0.f;
#pragma unroll
        for (int j = 0; j < K1; ++j)
          if (rmi & (1 << j)) s += Gcol[j];     // C1[i,j] in {0,1}
        float g = s, acc = s * c2reg[0];
        WALK15()
        gr += acc;
      }
      Kc[i] = gr;
      lo = fminf(lo, gr); hi = fmaxf(hi, gr);
    }
    lo = rmin16(lo); hi = rmax16(hi);
    float eps = 0.1f * (hi - lo) + TINYF;
    float sc = 1.4426950408889634f * __builtin_amdgcn_rcpf(eps);
#pragma unroll
    for (int i = 0; i < K1; ++i) {
      Kc[i] = __builtin_amdgcn_exp2f((lo - Kc[i]) * sc);
      Ksh[tb + i*17 + l] = Kc[i];           // transpose write (same wave)
    }
    // row l of K for the u-update
    float Krow[16];
#pragma unroll
    for (int jq = 0; jq < 4; ++jq) {
      float4 v = *(const float4*)&Ksh[tb + l*17 + jq*4];
      Krow[jq*4+0]=v.x; Krow[jq*4+1]=v.y; Krow[jq*4+2]=v.z; Krow[jq*4+3]=v.w;
    }

    // Sinkhorn: 5 iters (u then v), v0 = 1
    float vlane = 1.f;
    Vsh[tid] = 1.f;
#pragma unroll 1
    for (int it = 0; it < 5; ++it) {
      float vr[16];
#pragma unroll
      for (int q = 0; q < 4; ++q) {
        float4 v = *(const float4*)&Vsh[t*16 + q*4];
        vr[q*4+0]=v.x; vr[q*4+1]=v.y; vr[q*4+2]=v.z; vr[q*4+3]=v.w;
      }
      float w = 0.f;
#pragma unroll
      for (int j = 0; j < 16; ++j) w = fmaf(Krow[j], vr[j], w);
      float w16 = rsum16(Kc[16] * vlane);          // row 16 via DPP
      float um = (1.f/17.f) * rcpn(fmaxf(w,   TINYF));
      u16      = (1.f/17.f) * rcpn(fmaxf(w16, TINYF));
      Ush[tid] = um;
#pragma unroll
      for (int q = 0; q < 4; ++q) {
        float4 v = *(const float4*)&Ush[t*16 + q*4];
        ur[q*4+0]=v.x; ur[q*4+1]=v.y; ur[q*4+2]=v.z; ur[q*4+3]=v.w;
      }
      float sg = u16 * Kc[16];
#pragma unroll
      for (int k = 0; k < 16; ++k) sg = fmaf(ur[k], Kc[k], sg);
      vlane = q_l * rcpn(fmaxf(sg, TINYF));
      Vsh[tid] = vlane;
    }
    vm = vlane;
    // G = u * K * v
#pragma unroll
    for (int k = 0; k < 16; ++k) Gcol[k] = ur[k] * Kc[k] * vm;
    Gcol[16] = u16 * Kc[16] * vm;
  }

  // out[n,t] = sum_{i,l} (Mcol + delta) * G
  float acc1 = 0.f;
#pragma unroll
  for (int i = 0; i < K1; ++i) acc1 = fmaf(Mcol[i], Gcol[i], acc1);
#pragma unroll
  for (int i = 0; i < K1; ++i) {
    int rmi = __builtin_amdgcn_readfirstlane(rmv[i]);
    if (rmi) {
      float s = 0.f;
#pragma unroll
      for (int j = 0; j < K1; ++j)
        if (rmi & (1 << j)) s += Gcol[j];
      float g = s, acc = s * c2reg[0];
      WALK15()
      acc1 = fmaf(acc, Gcol[i], acc1);
    }
  }
  float accout = rsum16(acc1);
  if (l == 0) out[n*16 + t] = accout;
}

// ---------------------------------------------------------------------------
extern "C" void kernel_launch(void* const* d_in, const int* in_sizes, int n_in,
                              void* d_out, int out_size, void* d_ws, size_t ws_size,
                              hipStream_t stream) {
  const float* x          = (const float*)d_in[0];
  const float* adj        = (const float*)d_in[1];
  const int*   neighbors  = (const int*)  d_in[2];
  const float* templates_ = (const float*)d_in[3];
  const float* tfeat      = (const float*)d_in[4];
  const float* q0         = (const float*)d_in[5];
  const float* alpha0     = (const float*)d_in[6];
  float* out = (float*)d_out;

  float* ws     = (float*)d_ws;
  float* P      = ws;                       // 1048576 floats
  float* xsq    = P + 4096*256;             // 4096
  float* tfsq   = xsq + 4096;               // 256
  float* qmat   = tfsq + 256;               // 256
  float* cq     = qmat + 256;               // 256
  float* walpha = cq + 256;                 // 8 (padded for alignment)
  unsigned long long* pk = (unsigned long long*)(walpha + 8);  // 2 MB

  hipLaunchKernelGGL(prep_combined, dim3(PG_TOT), dim3(256), 0, stream,
                     x, adj, templates_, tfeat, q0, alpha0,
                     P, pk, xsq, tfsq, qmat, cq, walpha);
  hipLaunchKernelGGL(ltfgw_main, dim3(4096), dim3(256), 0, stream,
                     P, (const unsigned*)pk, xsq, tfsq, qmat, cq, walpha,
                     neighbors, templates_, out);
}